// Round 5
// baseline (135.686 us; speedup 1.0000x reference)
//
#include <hip/hip_runtime.h>
#include <stdint.h>

// TBN BasicBlock on MI355X, round 5: int8, 4 blocks/CU, 32x32x32 MFMA.
//   out = x + conv3x3(sign(bn2(conv3x3(sign(bn1(x)), tern(w1)))), tern(w2))
// Conv: BM=256 pixels (8 image rows) x BN=32 cout per block, 4 waves.
// Wave tile 64x32: 2 m-tiles, each one image row (32 px), via
// mfma_i32_32x32x32_i8 (4 MFMA + 6 ds_read_b128 per tap).
// K-loop = 4 ci-chunks of 64; per chunk all nine tap-panels LDS-resident.
// LDS: A [4 slots][321 px][16B]=20544 + B [9][4][32][16]=18432 -> 38976 B
// -> 4 blocks/CU, 16 waves/CU. 7 barriers per block total.

#define EPS 1e-5f

typedef int i32x4  __attribute__((ext_vector_type(4)));
typedef int i32x16 __attribute__((ext_vector_type(16)));

__device__ __forceinline__ void gload16(const void* g, void* l) {
  __builtin_amdgcn_global_load_lds(
      (const __attribute__((address_space(1))) void*)g,
      (__attribute__((address_space(3))) void*)l, 16, 0, 0);
}

// ---------------- stage 1: sum |w| (deterministic 2-level reduction) --------
__global__ __launch_bounds__(256) void wsum_kernel(const float* __restrict__ w,
                                                   float* __restrict__ partial) {
  __shared__ float red[256];
  const int t = threadIdx.x;
  const int b = blockIdx.x;
  float s = 0.f;
#pragma unroll
  for (int i = 0; i < 32; ++i) s += fabsf(w[b * 256 + t + i * 18432]);
  red[t] = s;
  __syncthreads();
  for (int o = 128; o > 0; o >>= 1) {
    if (t < o) red[t] += red[t + o];
    __syncthreads();
  }
  if (t == 0) partial[b] = red[0];
}

__global__ void delta_kernel(const float* __restrict__ p1, const float* __restrict__ p2,
                             float* __restrict__ delta) {
  const int t = threadIdx.x;
  if (t < 2) {
    const float* p = (t == 0) ? p1 : p2;
    double s = 0.0;
    for (int i = 0; i < 72; ++i) s += (double)p[i];
    delta[t] = 0.7f * (float)(s * (1.0 / 589824.0));
  }
}

// ------------- stage 2: quantize + transpose weights, alpha partials --------
// Weight global layout == the LDS layout the conv stages linearly:
//   nb=co>>5, colocal=co&31, chunk=ci>>6, slot=(ci&63)>>4, b=ci&15
//   off = nb*73728 + chunk*18432 + tap*2048 + slot*512 + colocal*16 + b
__global__ __launch_bounds__(256) void quant_kernel(const float* __restrict__ w,
                                                    const float* __restrict__ delta2, const int didx,
                                                    int8_t* __restrict__ wq,
                                                    float* __restrict__ psum,
                                                    float* __restrict__ pcnt) {
  __shared__ float rs[256];
  __shared__ float rc[256];
  const int t = threadIdx.x;
  const int idx = blockIdx.x * 256 + t;
  const float d = delta2[didx];
  const float v = w[idx];
  const float av = fabsf(v);
  const bool m = av > d;
  const int co = idx / 2304;
  const int rem = idx - co * 2304;
  const int ci = rem / 9;
  const int tap = rem - ci * 9;
  wq[(co >> 5) * 73728 + (ci >> 6) * 18432 + tap * 2048 +
     (((ci & 63) >> 4) << 9) + ((co & 31) << 4) + (ci & 15)] =
      m ? (v > 0.f ? (int8_t)1 : (int8_t)-1) : (int8_t)0;
  rs[t] = m ? av : 0.f;
  rc[t] = m ? 1.f : 0.f;
  __syncthreads();
  for (int o = 128; o > 0; o >>= 1) {
    if (t < o) { rs[t] += rs[t + o]; rc[t] += rc[t + o]; }
    __syncthreads();
  }
  if (t == 0) { psum[blockIdx.x] = rs[0]; pcnt[blockIdx.x] = rc[0]; }
}

__global__ __launch_bounds__(256) void alpha_kernel(const float* __restrict__ ps1, const float* __restrict__ pc1,
                                                    const float* __restrict__ ps2, const float* __restrict__ pc2,
                                                    const float* __restrict__ g2, const float* __restrict__ b2,
                                                    const float* __restrict__ m2, const float* __restrict__ v2,
                                                    float* __restrict__ alphas,
                                                    float* __restrict__ inv2o, float* __restrict__ add2o) {
  __shared__ float rs[256];
  __shared__ float rc[256];
  const int t = threadIdx.x;
  float s1 = 0.f, c1 = 0.f, s2 = 0.f, c2 = 0.f;
#pragma unroll
  for (int i = 0; i < 9; ++i) {
    s1 += ps1[t + (i << 8)]; c1 += pc1[t + (i << 8)];
    s2 += ps2[t + (i << 8)]; c2 += pc2[t + (i << 8)];
  }
  rs[t] = s1; rc[t] = c1;
  __syncthreads();
  for (int o = 128; o > 0; o >>= 1) {
    if (t < o) { rs[t] += rs[t + o]; rc[t] += rc[t + o]; }
    __syncthreads();
  }
  if (t == 0) alphas[0] = rs[0] / fmaxf(rc[0], 1.f);
  __syncthreads();
  rs[t] = s2; rc[t] = c2;
  __syncthreads();
  for (int o = 128; o > 0; o >>= 1) {
    if (t < o) { rs[t] += rs[t + o]; rc[t] += rc[t + o]; }
    __syncthreads();
  }
  if (t == 0) alphas[1] = rs[0] / fmaxf(rc[0], 1.f);
  const float inv = g2[t] * rsqrtf(v2[t] + EPS);
  inv2o[t] = inv;
  add2o[t] = b2[t] - m2[t] * inv;
}

// -------- stage 3: bn1 + binarize + NCHW -> NHWC (+-1 int8) -----------------
__global__ __launch_bounds__(256) void bn_bin_kernel(const float* __restrict__ x,
                                                     const float* __restrict__ g1,
                                                     const float* __restrict__ b1,
                                                     const float* __restrict__ m1,
                                                     const float* __restrict__ v1,
                                                     int8_t* __restrict__ a1) {
  __shared__ int8_t lds[64 * 40];
  const int t = threadIdx.x;
  const int p0 = blockIdx.x << 6;
  const int c0 = blockIdx.y << 5;
  const int n = blockIdx.z;
  const int pl = t & 63;
  const int cl0 = t >> 6;
#pragma unroll
  for (int i = 0; i < 8; ++i) {
    const int cl = cl0 + (i << 2);
    const int c = c0 + cl;
    const float inv = g1[c] * rsqrtf(v1[c] + EPS);
    const float ad = b1[c] - m1[c] * inv;
    const float val = x[(((n << 8) + c) << 10) + p0 + pl];
    const float tt = fmaf(val, inv, ad);
    lds[pl * 40 + cl] = (tt >= 0.f) ? (int8_t)1 : (int8_t)-1;
  }
  __syncthreads();
  const int pl2 = t >> 2;
  const int s2 = (t & 3) << 3;
  const uint2 o = *(const uint2*)&lds[pl2 * 40 + s2];
  *(uint2*)&a1[(((n << 10) + p0 + pl2) << 8) + c0 + s2] = o;
}

// -------- stages 4/5: per-chunk implicit-GEMM conv3x3 (i8 32x32 MFMA) -------
template <int EPI>
__global__ __launch_bounds__(256, 4) void conv3x3_tbn(
    const int8_t* __restrict__ act,   // NHWC int8 [B*1024][256]
    const int8_t* __restrict__ wq,    // [nb8][chunk4][tap9][slot4][co32][16]
    const float* __restrict__ alphas, const int aidx,
    const float* __restrict__ inv2, const float* __restrict__ add2,  // EPI==0
    const float* __restrict__ xres,                                  // EPI==1
    int8_t* __restrict__ aout, float* __restrict__ fout) {
  __shared__ int8_t ldsA[4 * 321 * 16];     // [slot][px 320 + zero][16B]; 20544 B
  __shared__ int8_t ldsB[9 * 4 * 32 * 16];  // [tap][slot][co 32][16B]; 18432 B

  const int tid = threadIdx.x;
  const int bid = blockIdx.x;
  const int L = (bid & 7) * 256 + (bid >> 3);  // XCD swizzle, 2048 blocks
  const int mb = L >> 3;            // 256 pixel tiles (8 image rows each)
  const int nb = L & 7;             // cout eighth (32 couts)
  const int n = mb >> 2;
  const int y0 = (mb & 3) << 3;
  const int l = tid & 63;
  const int wid = tid >> 6;
  const int lx = l & 31;            // x position / co
  const int lh = l >> 5;            // k-half selector

  // ---- A staging: 1280 dest slots = [slot 4][px 320], 16B each.
  // 320 = 5*64 -> slot boundaries wave-aligned -> wave-uniform-base+lane*16.
  int srcA[5], dstA[5];
#pragma unroll
  for (int i = 0; i < 5; ++i) {
    const int idx = tid + (i << 8);
    const int asl = idx / 320;
    const int apx = idx - asl * 320;
    int ys = y0 - 1 + (apx >> 5);
    ys = ys < 0 ? 0 : (ys > 31 ? 31 : ys);  // clamp (OOB rows only read via zero-px)
    srcA[i] = (((n << 10) + (ys << 5) + (apx & 31)) << 8) + (asl << 4);
    dstA[i] = asl * 5136 + (apx << 4);
  }
  if (tid < 4) *(i32x4*)(ldsA + tid * 5136 + 5120) = (i32x4){0, 0, 0, 0};

  i32x16 acc[2];
  acc[0] = (i32x16)(0);
  acc[1] = (i32x16)(0);

  const int8_t* wbase = wq + nb * 73728;

  // ---- prologue: stage chunk 0 ----
#pragma unroll
  for (int i = 0; i < 5; ++i) gload16(act + srcA[i], ldsA + dstA[i]);
#pragma unroll
  for (int i = 0; i < 4; ++i)
    gload16(wbase + ((tid + (i << 8)) << 4), ldsB + ((tid + (i << 8)) << 4));
  if (tid < 128) gload16(wbase + ((tid + 1024) << 4), ldsB + ((tid + 1024) << 4));
  __syncthreads();  // implicit vmcnt(0): staged data visible

  for (int chunk = 0; chunk < 4; ++chunk) {
    __builtin_amdgcn_s_setprio(1);
    // ---- barrier-free 9-tap compute over resident chunk ----
#pragma unroll
    for (int tap = 0; tap < 9; ++tap) {
      const int ky = tap / 3, kx = tap % 3;
      const int xs = lx + kx - 1;
      const bool xok = (unsigned)xs < 32u;
      int apix[2];
#pragma unroll
      for (int mt = 0; mt < 2; ++mt) {
        const int yr = (wid << 1) + mt + ky;       // A-tile row 0..9
        const bool ok = xok && ((unsigned)(y0 - 1 + yr) < 32u);
        apix[mt] = ok ? (yr << 5) + xs : 320;      // zero-px for halo
      }
      i32x4 bfr[2], afr[2][2];
#pragma unroll
      for (int kh = 0; kh < 2; ++kh) {
        const int sl = lh + (kh << 1);
        bfr[kh] = *(const i32x4*)(ldsB + (tap << 11) + (sl << 9) + (lx << 4));
#pragma unroll
        for (int mt = 0; mt < 2; ++mt)
          afr[mt][kh] = *(const i32x4*)(ldsA + sl * 5136 + (apix[mt] << 4));
      }
#pragma unroll
      for (int mt = 0; mt < 2; ++mt)
#pragma unroll
        for (int kh = 0; kh < 2; ++kh)
          acc[mt] = __builtin_amdgcn_mfma_i32_32x32x32_i8(afr[mt][kh], bfr[kh], acc[mt], 0, 0, 0);
    }
    __builtin_amdgcn_s_setprio(0);
    // ---- restage for next chunk ----
    if (chunk < 3) {
      __syncthreads();  // all waves done reading this chunk
#pragma unroll
      for (int i = 0; i < 5; ++i)
        gload16(act + srcA[i] + ((chunk + 1) << 6), ldsA + dstA[i]);
      const int8_t* wch = wbase + (chunk + 1) * 18432;
#pragma unroll
      for (int i = 0; i < 4; ++i)
        gload16(wch + ((tid + (i << 8)) << 4), ldsB + ((tid + (i << 8)) << 4));
      if (tid < 128) gload16(wch + ((tid + 1024) << 4), ldsB + ((tid + 1024) << 4));
      __syncthreads();  // drain
    }
  }

  // C/D (32x32): col = lane&31, row = (reg&3) + 8*(reg>>2) + 4*(lane>>5)
  const float alpha = alphas[aidx];
  const int co = (nb << 5) + lx;
  if constexpr (EPI == 0) {
    const float inv = inv2[co];
    const float ad = add2[co];
#pragma unroll
    for (int mt = 0; mt < 2; ++mt) {
      const int pixbase = (mb << 8) + (((wid << 1) + mt) << 5) + (lh << 2);
#pragma unroll
      for (int rg = 0; rg < 16; ++rg) {
        const int pix = pixbase + (rg & 3) + ((rg >> 2) << 3);
        const float h = alpha * (float)acc[mt][rg];
        const float tt = fmaf(h, inv, ad);
        aout[(pix << 8) + co] = (tt >= 0.f) ? (int8_t)1 : (int8_t)-1;
      }
    }
  } else {
#pragma unroll
    for (int mt = 0; mt < 2; ++mt) {
      const int pimg0 = ((mb & 3) << 8) + (((wid << 1) + mt) << 5) + (lh << 2);
#pragma unroll
      for (int qd = 0; qd < 4; ++qd) {
        const int off = (((n << 8) + co) << 10) + pimg0 + (qd << 3);
        const float4 xv = *(const float4*)(xres + off);
        float4 o;
        o.x = xv.x + alpha * (float)acc[mt][qd * 4 + 0];
        o.y = xv.y + alpha * (float)acc[mt][qd * 4 + 1];
        o.z = xv.z + alpha * (float)acc[mt][qd * 4 + 2];
        o.w = xv.w + alpha * (float)acc[mt][qd * 4 + 3];
        *(float4*)(fout + off) = o;
      }
    }
  }
}

extern "C" void kernel_launch(void* const* d_in, const int* in_sizes, int n_in,
                              void* d_out, int out_size, void* d_ws, size_t ws_size,
                              hipStream_t stream) {
  const float* x  = (const float*)d_in[0];
  const float* g1 = (const float*)d_in[1];
  const float* b1 = (const float*)d_in[2];
  const float* m1 = (const float*)d_in[3];
  const float* v1 = (const float*)d_in[4];
  const float* w1 = (const float*)d_in[5];
  const float* g2 = (const float*)d_in[6];
  const float* b2 = (const float*)d_in[7];
  const float* m2 = (const float*)d_in[8];
  const float* v2 = (const float*)d_in[9];
  const float* w2 = (const float*)d_in[10];
  float* out = (float*)d_out;

  char* ws = (char*)d_ws;
  int8_t* a1  = (int8_t*)(ws);                       // 16 MB
  int8_t* a2  = (int8_t*)(ws + 16777216);            // 16 MB
  int8_t* wq1 = (int8_t*)(ws + 33554432);            // 576 KB
  int8_t* wq2 = (int8_t*)(ws + 33554432 + 589824);   // 576 KB
  float* fs = (float*)(ws + 33554432 + 1179648);
  float* pd1    = fs;
  float* pd2    = fs + 128;
  float* deltas = fs + 256;
  float* alphas = fs + 260;
  float* ps1    = fs + 512;
  float* pc1    = fs + 512 + 2304;
  float* ps2    = fs + 512 + 4608;
  float* pc2    = fs + 512 + 6912;
  float* inv2   = fs + 512 + 9216;
  float* add2   = fs + 512 + 9472;

  hipLaunchKernelGGL(wsum_kernel, dim3(72), dim3(256), 0, stream, w1, pd1);
  hipLaunchKernelGGL(wsum_kernel, dim3(72), dim3(256), 0, stream, w2, pd2);
  hipLaunchKernelGGL(delta_kernel, dim3(1), dim3(64), 0, stream, pd1, pd2, deltas);
  hipLaunchKernelGGL(quant_kernel, dim3(2304), dim3(256), 0, stream, w1, deltas, 0, wq1, ps1, pc1);
  hipLaunchKernelGGL(quant_kernel, dim3(2304), dim3(256), 0, stream, w2, deltas, 1, wq2, ps2, pc2);
  hipLaunchKernelGGL(alpha_kernel, dim3(1), dim3(256), 0, stream,
                     ps1, pc1, ps2, pc2, g2, b2, m2, v2, alphas, inv2, add2);
  hipLaunchKernelGGL(bn_bin_kernel, dim3(16, 8, 64), dim3(256), 0, stream, x, g1, b1, m1, v1, a1);
  hipLaunchKernelGGL((conv3x3_tbn<0>), dim3(2048), dim3(256), 0, stream,
                     a1, wq1, alphas, 0, inv2, add2, (const float*)nullptr,
                     a2, (float*)nullptr);
  hipLaunchKernelGGL((conv3x3_tbn<1>), dim3(2048), dim3(256), 0, stream,
                     a2, wq2, alphas, 1, (const float*)nullptr, (const float*)nullptr, x,
                     (int8_t*)nullptr, out);
  (void)in_sizes; (void)n_in; (void)out_size; (void)ws_size;
}

// Round 6
// 132.307 us; speedup vs baseline: 1.0255x; 1.0255x over previous
//
#include <hip/hip_runtime.h>
#include <stdint.h>

// TBN BasicBlock on MI355X, round 6: int8, 64x64 wave tile, 16 waves/CU.
//   out = x + conv3x3(sign(bn2(conv3x3(sign(bn1(x)), tern(w1)))), tern(w2))
// Conv: BM=512 pixels (16 image rows) x BN=64 cout per block, 8 waves (512
// threads), wave tile 64x64 via mfma_i32_32x32x32_i8: per tap 8 ds_read_b128
// (4 A + 4 B) feed 8 MFMAs (1.0 KB LDS per MFMA), 4 independent acc chains.
// K-loop = 4 ci-chunks of 64; per chunk all nine tap-panels LDS-resident.
// LDS: A [4 slots][577 px][16B]=36928 + B [9][4][64][16]=36864 -> 73792 B
// -> 2 blocks/CU, 16 waves/CU. 7 barriers per block total.

#define EPS 1e-5f

typedef int i32x4  __attribute__((ext_vector_type(4)));
typedef int i32x16 __attribute__((ext_vector_type(16)));

__device__ __forceinline__ void gload16(const void* g, void* l) {
  __builtin_amdgcn_global_load_lds(
      (const __attribute__((address_space(1))) void*)g,
      (__attribute__((address_space(3))) void*)l, 16, 0, 0);
}

// ---------------- stage 1: sum |w| (deterministic 2-level reduction) --------
__global__ __launch_bounds__(256) void wsum_kernel(const float* __restrict__ w,
                                                   float* __restrict__ partial) {
  __shared__ float red[256];
  const int t = threadIdx.x;
  const int b = blockIdx.x;
  float s = 0.f;
#pragma unroll
  for (int i = 0; i < 32; ++i) s += fabsf(w[b * 256 + t + i * 18432]);
  red[t] = s;
  __syncthreads();
  for (int o = 128; o > 0; o >>= 1) {
    if (t < o) red[t] += red[t + o];
    __syncthreads();
  }
  if (t == 0) partial[b] = red[0];
}

__global__ void delta_kernel(const float* __restrict__ p1, const float* __restrict__ p2,
                             float* __restrict__ delta) {
  const int t = threadIdx.x;
  if (t < 2) {
    const float* p = (t == 0) ? p1 : p2;
    double s = 0.0;
    for (int i = 0; i < 72; ++i) s += (double)p[i];
    delta[t] = 0.7f * (float)(s * (1.0 / 589824.0));
  }
}

// ------------- stage 2: quantize + transpose weights, alpha partials --------
// Weight global layout == the LDS layout the conv stages linearly:
//   nb=co>>6, chunk=ci>>6, slot=(ci&63)>>4, b=ci&15
//   off = nb*147456 + chunk*36864 + tap*4096 + slot*1024 + (co&63)*16 + b
__global__ __launch_bounds__(256) void quant_kernel(const float* __restrict__ w,
                                                    const float* __restrict__ delta2, const int didx,
                                                    int8_t* __restrict__ wq,
                                                    float* __restrict__ psum,
                                                    float* __restrict__ pcnt) {
  __shared__ float rs[256];
  __shared__ float rc[256];
  const int t = threadIdx.x;
  const int idx = blockIdx.x * 256 + t;
  const float d = delta2[didx];
  const float v = w[idx];
  const float av = fabsf(v);
  const bool m = av > d;
  const int co = idx / 2304;
  const int rem = idx - co * 2304;
  const int ci = rem / 9;
  const int tap = rem - ci * 9;
  wq[(co >> 6) * 147456 + (ci >> 6) * 36864 + tap * 4096 +
     (((ci & 63) >> 4) << 10) + ((co & 63) << 4) + (ci & 15)] =
      m ? (v > 0.f ? (int8_t)1 : (int8_t)-1) : (int8_t)0;
  rs[t] = m ? av : 0.f;
  rc[t] = m ? 1.f : 0.f;
  __syncthreads();
  for (int o = 128; o > 0; o >>= 1) {
    if (t < o) { rs[t] += rs[t + o]; rc[t] += rc[t + o]; }
    __syncthreads();
  }
  if (t == 0) { psum[blockIdx.x] = rs[0]; pcnt[blockIdx.x] = rc[0]; }
}

__global__ __launch_bounds__(256) void alpha_kernel(const float* __restrict__ ps1, const float* __restrict__ pc1,
                                                    const float* __restrict__ ps2, const float* __restrict__ pc2,
                                                    const float* __restrict__ g2, const float* __restrict__ b2,
                                                    const float* __restrict__ m2, const float* __restrict__ v2,
                                                    float* __restrict__ alphas,
                                                    float* __restrict__ inv2o, float* __restrict__ add2o) {
  __shared__ float rs[256];
  __shared__ float rc[256];
  const int t = threadIdx.x;
  float s1 = 0.f, c1 = 0.f, s2 = 0.f, c2 = 0.f;
#pragma unroll
  for (int i = 0; i < 9; ++i) {
    s1 += ps1[t + (i << 8)]; c1 += pc1[t + (i << 8)];
    s2 += ps2[t + (i << 8)]; c2 += pc2[t + (i << 8)];
  }
  rs[t] = s1; rc[t] = c1;
  __syncthreads();
  for (int o = 128; o > 0; o >>= 1) {
    if (t < o) { rs[t] += rs[t + o]; rc[t] += rc[t + o]; }
    __syncthreads();
  }
  if (t == 0) alphas[0] = rs[0] / fmaxf(rc[0], 1.f);
  __syncthreads();
  rs[t] = s2; rc[t] = c2;
  __syncthreads();
  for (int o = 128; o > 0; o >>= 1) {
    if (t < o) { rs[t] += rs[t + o]; rc[t] += rc[t + o]; }
    __syncthreads();
  }
  if (t == 0) alphas[1] = rs[0] / fmaxf(rc[0], 1.f);
  const float inv = g2[t] * rsqrtf(v2[t] + EPS);
  inv2o[t] = inv;
  add2o[t] = b2[t] - m2[t] * inv;
}

// -------- stage 3: bn1 + binarize + NCHW -> NHWC (+-1 int8) -----------------
__global__ __launch_bounds__(256) void bn_bin_kernel(const float* __restrict__ x,
                                                     const float* __restrict__ g1,
                                                     const float* __restrict__ b1,
                                                     const float* __restrict__ m1,
                                                     const float* __restrict__ v1,
                                                     int8_t* __restrict__ a1) {
  __shared__ int8_t lds[64 * 40];
  const int t = threadIdx.x;
  const int p0 = blockIdx.x << 6;
  const int c0 = blockIdx.y << 5;
  const int n = blockIdx.z;
  const int pl = t & 63;
  const int cl0 = t >> 6;
#pragma unroll
  for (int i = 0; i < 8; ++i) {
    const int cl = cl0 + (i << 2);
    const int c = c0 + cl;
    const float inv = g1[c] * rsqrtf(v1[c] + EPS);
    const float ad = b1[c] - m1[c] * inv;
    const float val = x[(((n << 8) + c) << 10) + p0 + pl];
    const float tt = fmaf(val, inv, ad);
    lds[pl * 40 + cl] = (tt >= 0.f) ? (int8_t)1 : (int8_t)-1;
  }
  __syncthreads();
  const int pl2 = t >> 2;
  const int s2 = (t & 3) << 3;
  const uint2 o = *(const uint2*)&lds[pl2 * 40 + s2];
  *(uint2*)&a1[(((n << 10) + p0 + pl2) << 8) + c0 + s2] = o;
}

// -------- stages 4/5: per-chunk implicit-GEMM conv3x3 (i8 32x32 MFMA) -------
template <int EPI>
__global__ __launch_bounds__(512, 4) void conv3x3_tbn(
    const int8_t* __restrict__ act,   // NHWC int8 [B*1024][256]
    const int8_t* __restrict__ wq,    // [nb4][chunk4][tap9][slot4][co64][16]
    const float* __restrict__ alphas, const int aidx,
    const float* __restrict__ inv2, const float* __restrict__ add2,  // EPI==0
    const float* __restrict__ xres,                                  // EPI==1
    int8_t* __restrict__ aout, float* __restrict__ fout) {
  __shared__ int8_t ldsA[4 * 577 * 16];     // [slot][px 576 + zero][16B]; 36928 B
  __shared__ int8_t ldsB[9 * 4 * 64 * 16];  // [tap][slot][co 64][16B];   36864 B

  const int tid = threadIdx.x;
  const int bid = blockIdx.x;
  const int L = (bid & 7) * 64 + (bid >> 3);  // XCD swizzle, 512 blocks
  const int mb = L >> 2;            // 128 pixel tiles (16 image rows each)
  const int nb = L & 3;             // cout quarter (64 couts)
  const int n = mb >> 1;
  const int y0 = (mb & 1) << 4;
  const int l = tid & 63;
  const int wid = tid >> 6;         // 8 waves, 2 image rows each
  const int lx = l & 31;            // x position / co lane
  const int lh = l >> 5;            // k-half selector

  // ---- A staging: 2304 dest slots = [slot 4][px 576], 16B each.
  // 576 = 9*64 -> slot boundaries wave-aligned -> wave-uniform-base+lane*16.
  int srcA[5];
#pragma unroll
  for (int i = 0; i < 5; ++i) {
    const int idx = tid + (i << 9);
    const int asl = idx / 576;
    const int apx = idx - asl * 576;
    int ys = y0 - 1 + (apx >> 5);
    ys = ys < 0 ? 0 : (ys > 31 ? 31 : ys);  // clamp (OOB rows only read via zero-px)
    srcA[i] = (((n << 10) + (ys << 5) + (apx & 31)) << 8) + (asl << 4);
  }
  if (tid < 4) *(i32x4*)(ldsA + tid * 9232 + 9216) = (i32x4){0, 0, 0, 0};

  i32x16 acc[2][2];
  acc[0][0] = (i32x16)(0); acc[0][1] = (i32x16)(0);
  acc[1][0] = (i32x16)(0); acc[1][1] = (i32x16)(0);

  const int8_t* wbase = wq + nb * 147456;

  // ---- prologue: stage chunk 0 ----
#pragma unroll
  for (int i = 0; i < 5; ++i) {
    const int idx = tid + (i << 9);
    if (i < 4 || tid < 256) {
      const int asl = idx / 576;
      const int apx = idx - asl * 576;
      gload16(act + srcA[i], ldsA + asl * 9232 + (apx << 4));
      gload16(wbase + (idx << 4), ldsB + (idx << 4));
    }
  }
  __syncthreads();  // implicit vmcnt(0): staged data visible

  for (int chunk = 0; chunk < 4; ++chunk) {
    __builtin_amdgcn_s_setprio(1);
    // ---- barrier-free 9-tap compute over resident chunk ----
#pragma unroll
    for (int tap = 0; tap < 9; ++tap) {
      const int ky = tap / 3, kx = tap % 3;
      const int xs = lx + kx - 1;
      const bool xok = (unsigned)xs < 32u;
      int apix[2];
#pragma unroll
      for (int mt = 0; mt < 2; ++mt) {
        const int yr = (wid << 1) + mt + ky;       // A-tile row 0..17
        const bool ok = xok && ((unsigned)(y0 - 1 + yr) < 32u);
        apix[mt] = ok ? (yr << 5) + xs : 576;      // zero-px for halo
      }
      i32x4 afr[2][2], bfr[2][2];
#pragma unroll
      for (int kh = 0; kh < 2; ++kh) {
        const int sl = lh + (kh << 1);
#pragma unroll
        for (int mt = 0; mt < 2; ++mt)
          afr[mt][kh] = *(const i32x4*)(ldsA + sl * 9232 + (apix[mt] << 4));
#pragma unroll
        for (int nt = 0; nt < 2; ++nt)
          bfr[nt][kh] = *(const i32x4*)(ldsB + (tap << 12) + (sl << 10) + ((nt << 5) + lx) * 16);
      }
#pragma unroll
      for (int mt = 0; mt < 2; ++mt)
#pragma unroll
        for (int nt = 0; nt < 2; ++nt)
#pragma unroll
          for (int kh = 0; kh < 2; ++kh)
            acc[mt][nt] = __builtin_amdgcn_mfma_i32_32x32x32_i8(afr[mt][kh], bfr[nt][kh], acc[mt][nt], 0, 0, 0);
    }
    __builtin_amdgcn_s_setprio(0);
    // ---- restage for next chunk ----
    if (chunk < 3) {
      __syncthreads();  // all waves done reading this chunk
      const int8_t* wch = wbase + (chunk + 1) * 36864;
#pragma unroll
      for (int i = 0; i < 5; ++i) {
        const int idx = tid + (i << 9);
        if (i < 4 || tid < 256) {
          const int asl = idx / 576;
          const int apx = idx - asl * 576;
          gload16(act + srcA[i] + ((chunk + 1) << 6), ldsA + asl * 9232 + (apx << 4));
          gload16(wch + (idx << 4), ldsB + (idx << 4));
        }
      }
      __syncthreads();  // drain
    }
  }

  // C/D (32x32): n(co) = lane&31, m(x) = (reg&3) + 8*(reg>>2) + 4*(lane>>5)
  const float alpha = alphas[aidx];
  if constexpr (EPI == 0) {
#pragma unroll
    for (int nt = 0; nt < 2; ++nt) {
      const int co = (nb << 6) + (nt << 5) + lx;
      const float inv = inv2[co];
      const float ad = add2[co];
#pragma unroll
      for (int mt = 0; mt < 2; ++mt) {
        const int pixbase = (mb << 9) + (((wid << 1) + mt) << 5) + (lh << 2);
#pragma unroll
        for (int rg = 0; rg < 16; ++rg) {
          const int pix = pixbase + (rg & 3) + ((rg >> 2) << 3);
          const float h = alpha * (float)acc[mt][nt][rg];
          const float tt = fmaf(h, inv, ad);
          aout[(pix << 8) + co] = (tt >= 0.f) ? (int8_t)1 : (int8_t)-1;
        }
      }
    }
  } else {
#pragma unroll
    for (int nt = 0; nt < 2; ++nt) {
      const int co = (nb << 6) + (nt << 5) + lx;
#pragma unroll
      for (int mt = 0; mt < 2; ++mt) {
        const int pimg0 = ((mb & 1) << 9) + (((wid << 1) + mt) << 5) + (lh << 2);
#pragma unroll
        for (int qd = 0; qd < 4; ++qd) {
          const int off = (((n << 8) + co) << 10) + pimg0 + (qd << 3);
          const float4 xv = *(const float4*)(xres + off);
          float4 o;
          o.x = xv.x + alpha * (float)acc[mt][nt][qd * 4 + 0];
          o.y = xv.y + alpha * (float)acc[mt][nt][qd * 4 + 1];
          o.z = xv.z + alpha * (float)acc[mt][nt][qd * 4 + 2];
          o.w = xv.w + alpha * (float)acc[mt][nt][qd * 4 + 3];
          *(float4*)(fout + off) = o;
        }
      }
    }
  }
}

extern "C" void kernel_launch(void* const* d_in, const int* in_sizes, int n_in,
                              void* d_out, int out_size, void* d_ws, size_t ws_size,
                              hipStream_t stream) {
  const float* x  = (const float*)d_in[0];
  const float* g1 = (const float*)d_in[1];
  const float* b1 = (const float*)d_in[2];
  const float* m1 = (const float*)d_in[3];
  const float* v1 = (const float*)d_in[4];
  const float* w1 = (const float*)d_in[5];
  const float* g2 = (const float*)d_in[6];
  const float* b2 = (const float*)d_in[7];
  const float* m2 = (const float*)d_in[8];
  const float* v2 = (const float*)d_in[9];
  const float* w2 = (const float*)d_in[10];
  float* out = (float*)d_out;

  char* ws = (char*)d_ws;
  int8_t* a1  = (int8_t*)(ws);                       // 16 MB
  int8_t* a2  = (int8_t*)(ws + 16777216);            // 16 MB
  int8_t* wq1 = (int8_t*)(ws + 33554432);            // 576 KB
  int8_t* wq2 = (int8_t*)(ws + 33554432 + 589824);   // 576 KB
  float* fs = (float*)(ws + 33554432 + 1179648);
  float* pd1    = fs;
  float* pd2    = fs + 128;
  float* deltas = fs + 256;
  float* alphas = fs + 260;
  float* ps1    = fs + 512;
  float* pc1    = fs + 512 + 2304;
  float* ps2    = fs + 512 + 4608;
  float* pc2    = fs + 512 + 6912;
  float* inv2   = fs + 512 + 9216;
  float* add2   = fs + 512 + 9472;

  hipLaunchKernelGGL(wsum_kernel, dim3(72), dim3(256), 0, stream, w1, pd1);
  hipLaunchKernelGGL(wsum_kernel, dim3(72), dim3(256), 0, stream, w2, pd2);
  hipLaunchKernelGGL(delta_kernel, dim3(1), dim3(64), 0, stream, pd1, pd2, deltas);
  hipLaunchKernelGGL(quant_kernel, dim3(2304), dim3(256), 0, stream, w1, deltas, 0, wq1, ps1, pc1);
  hipLaunchKernelGGL(quant_kernel, dim3(2304), dim3(256), 0, stream, w2, deltas, 1, wq2, ps2, pc2);
  hipLaunchKernelGGL(alpha_kernel, dim3(1), dim3(256), 0, stream,
                     ps1, pc1, ps2, pc2, g2, b2, m2, v2, alphas, inv2, add2);
  hipLaunchKernelGGL(bn_bin_kernel, dim3(16, 8, 64), dim3(256), 0, stream, x, g1, b1, m1, v1, a1);
  hipLaunchKernelGGL((conv3x3_tbn<0>), dim3(512), dim3(512), 0, stream,
                     a1, wq1, alphas, 0, inv2, add2, (const float*)nullptr,
                     a2, (float*)nullptr);
  hipLaunchKernelGGL((conv3x3_tbn<1>), dim3(512), dim3(512), 0, stream,
                     a2, wq2, alphas, 1, (const float*)nullptr, (const float*)nullptr, x,
                     (int8_t*)nullptr, out);
  (void)in_sizes; (void)n_in; (void)out_size; (void)ws_size;
}